// Round 1
// baseline (470.737 us; speedup 1.0000x reference)
//
#include <hip/hip_runtime.h>
#include <math.h>

// Problem constants (from reference)
#define GG 16
#define NNODE 512
#define EEDGE 2048
#define KEEPN 256
#define PITERS 64

#define NNT (GG*NNODE)   // 8192 total nodes
#define NET (GG*EEDGE)   // 32768 total edges
#define MN (2*GG*EEDGE)  // 65536 node-graph directed edges
#define ME (4*GG*EEDGE)  // 131072 edge-graph directed edges

// workspace float offsets
#define WS_C1N 0
#define WS_C2N 8192
#define WS_BN  16384
#define WS_D1N 24576
#define WS_D2N 32768
#define WS_E2N 40960
#define WS_SN  49152
#define WS_C1E 57344
#define WS_C2E 90112
#define WS_BE  122880
#define WS_D1E 155648
#define WS_D2E 188416
#define WS_E2E 221184
#define WS_SE  253952
#define WS_MASK 286720   // int[8192]
#define WS_KEEP 294912   // int[32768]
#define WS_KLIST 327680  // int[32768]
#define WS_KCNT 360448   // int[16]
#define WS_SCALE 360464  // float[16]
#define WS_TOTAL 360480

// output float offsets: xn | L0 | xe | L1
#define O_XN 0
#define O_L0 524288
#define O_XE 4718592
#define O_L1 6815744

// ---------------------------------------------------------------------------
// K2: per-row channel dots. One wave (64 lanes) per row; c_k = x_row . W_k.
// out = c0 + c1 + c2 stored as "base"; c1, c2 kept for message passing.
__global__ __launch_bounds__(256) void k_dots(const float* __restrict__ xn,
    const float* __restrict__ xe, const float* __restrict__ Wn,
    const float* __restrict__ We, float* __restrict__ ws) {
  int gw = (blockIdx.x * 256 + threadIdx.x) >> 6;
  int lane = threadIdx.x & 63;
  const float* x; const float* W; int row; float *c1, *c2, *bs;
  if (gw < NNT) {
    row = gw; x = xn + (size_t)row * 64; W = Wn;
    c1 = ws + WS_C1N; c2 = ws + WS_C2N; bs = ws + WS_BN;
  } else {
    row = gw - NNT; if (row >= NET) return;
    x = xe + (size_t)row * 64; W = We;
    c1 = ws + WS_C1E; c2 = ws + WS_C2E; bs = ws + WS_BE;
  }
  float v = x[lane];
  float r0 = v * W[lane];
  float r1 = v * W[64 + lane];
  float r2 = v * W[128 + lane];
  for (int o = 32; o; o >>= 1) {
    r0 += __shfl_xor(r0, o, 64);
    r1 += __shfl_xor(r1, o, 64);
    r2 += __shfl_xor(r2, o, 64);
  }
  if (lane == 0) { c1[row] = r1; c2[row] = r2; bs[row] = r0 + r1 + r2; }
}

// K3: d1 = L c1, d2 = L c2 (scalar scatter, both graphs)
__global__ __launch_bounds__(256) void k_scat1(
    const int* __restrict__ sn, const int* __restrict__ dn, const float* __restrict__ wn,
    const int* __restrict__ se, const int* __restrict__ de, const float* __restrict__ we,
    float* __restrict__ ws) {
  int t = blockIdx.x * 256 + threadIdx.x;
  if (t < MN) {
    int s = sn[t], d = dn[t]; float w = wn[t];
    atomicAdd(ws + WS_D1N + d, w * ws[WS_C1N + s]);
    atomicAdd(ws + WS_D2N + d, w * ws[WS_C2N + s]);
  } else {
    int t2 = t - MN; if (t2 >= ME) return;
    int s = se[t2], d = de[t2]; float w = we[t2];
    atomicAdd(ws + WS_D1E + d, w * ws[WS_C1E + s]);
    atomicAdd(ws + WS_D2E + d, w * ws[WS_C2E + s]);
  }
}

// K4: e2 = L d2 (needs d2 complete -> separate dispatch)
__global__ __launch_bounds__(256) void k_scat2(
    const int* __restrict__ sn, const int* __restrict__ dn, const float* __restrict__ wn,
    const int* __restrict__ se, const int* __restrict__ de, const float* __restrict__ we,
    float* __restrict__ ws) {
  int t = blockIdx.x * 256 + threadIdx.x;
  if (t < MN) {
    int s = sn[t], d = dn[t]; float w = wn[t];
    atomicAdd(ws + WS_E2N + d, w * ws[WS_D2N + s]);
  } else {
    int t2 = t - MN; if (t2 >= ME) return;
    int s = se[t2], d = de[t2]; float w = we[t2];
    atomicAdd(ws + WS_E2E + d, w * ws[WS_D2E + s]);
  }
}

// ---------------------------------------------------------------------------
// K6 "fat" kernel: blocks 0..15 do per-graph pooling (scores -> aug -> bitonic
// top-256 -> keep_e -> CSR -> 64 power iters -> scale). Blocks 16.. zero-fill
// the L0 and L1 output regions concurrently (independent work, same dispatch,
// hides the latency-bound pooling under 284 MB of streaming stores).
__global__ __launch_bounds__(512) void k_fat(
    const int* __restrict__ edge_u, const int* __restrict__ edge_v,
    const float* __restrict__ bn, const float* __restrict__ be,
    float* __restrict__ ws, float* __restrict__ out, int nzb) {
  const int tid = threadIdx.x;
  if (blockIdx.x >= 16) {
    // zero-fill L0 + L1 regions (xn/xe written densely by k_out)
    const long long L04 = 4194304 / 4;                 // 1,048,576 float4
    const long long TOT4 = (4194304LL + 67108864LL) / 4; // 17,825,792 float4
    float4 z4 = make_float4(0.f, 0.f, 0.f, 0.f);
    float4* o4 = (float4*)out;
    long long start = (long long)(blockIdx.x - 16) * 512 + tid;
    long long stride = (long long)nzb * 512;
    for (long long i = start; i < TOT4; i += stride) {
      long long f = (i < L04) ? (O_L0 / 4 + i) : (O_L1 / 4 + (i - L04));
      o4[f] = z4;
    }
    return;
  }
  const int g = blockIdx.x;
  __shared__ float aug[NNODE];
  __shared__ float key[NNODE];
  __shared__ int kidx[NNODE];
  __shared__ int su[EEDGE];
  __shared__ int sv[EEDGE];
  __shared__ int maskS[NNODE];
  __shared__ int degS[NNODE];
  __shared__ int offS[NNODE];
  __shared__ int adj[2 * EEDGE];
  __shared__ float wv[NNODE];
  __shared__ float red[8];
  __shared__ int kcnt;
  int* wsi = (int*)ws;

  // node scores for this graph + aug init
  float bn0 = bn[0], be0 = be[0];
  int nidx = g * NNODE + tid;
  {
    float t = ws[WS_BN + nidx] - ws[WS_D1N + nidx] - 2.0f * ws[WS_D2N + nidx]
            + 0.5f * ws[WS_E2N + nidx] + bn0;
    float s = 1.0f / (1.0f + expf(-t));
    ws[WS_SN + nidx] = s;
    aug[tid] = s;
  }
  for (int e = tid; e < EEDGE; e += 512) {
    su[e] = edge_u[g * EEDGE + e];
    sv[e] = edge_v[g * EEDGE + e];
  }
  if (tid == 0) kcnt = 0;
  maskS[tid] = 0;
  __syncthreads();
  // edge scores + scatter into aug at both endpoints
  for (int e = tid; e < EEDGE; e += 512) {
    int eidx = g * EEDGE + e;
    float t = ws[WS_BE + eidx] - ws[WS_D1E + eidx] - 2.0f * ws[WS_D2E + eidx]
            + 0.5f * ws[WS_E2E + eidx] + be0;
    float s = 1.0f / (1.0f + expf(-t));
    ws[WS_SE + eidx] = s;
    atomicAdd(&aug[su[e]], s);
    atomicAdd(&aug[sv[e]], s);
  }
  __syncthreads();
  // bitonic sort 512 elems: descending by value, ascending index on ties
  // (exactly replicates stable jnp.argsort(-aug))
  key[tid] = aug[tid]; kidx[tid] = tid;
  __syncthreads();
  for (int k = 2; k <= NNODE; k <<= 1) {
    for (int j = k >> 1; j > 0; j >>= 1) {
      int i = tid, ixj = i ^ j;
      if (ixj > i) {
        float ka = key[i], kb = key[ixj];
        int ia = kidx[i], ib = kidx[ixj];
        bool aAfter = (ka < kb) || (ka == kb && ia > ib); // a belongs after b (desc order)
        bool doswap = ((i & k) == 0) ? aAfter : !aAfter;
        if (doswap) { key[i] = kb; key[ixj] = ka; kidx[i] = ib; kidx[ixj] = ia; }
      }
      __syncthreads();
    }
  }
  if (tid < KEEPN) maskS[kidx[tid]] = 1;
  degS[tid] = 0;
  __syncthreads();
  wsi[WS_MASK + nidx] = maskS[tid];
  // keep_e + compact kept list + degree count
  for (int e = tid; e < EEDGE; e += 512) {
    int k = maskS[su[e]] & maskS[sv[e]];
    wsi[WS_KEEP + g * EEDGE + e] = k;
    if (k) {
      int p = atomicAdd(&kcnt, 1);
      wsi[WS_KLIST + g * EEDGE + p] = e;
      atomicAdd(&degS[su[e]], 1);
      atomicAdd(&degS[sv[e]], 1);
    }
  }
  __syncthreads();
  if (tid == 0) wsi[WS_KCNT + g] = kcnt;
  // exclusive prefix of deg -> offS (Hillis-Steele on reused key buffer)
  int* t0 = (int*)key;
  t0[tid] = degS[tid];
  __syncthreads();
  for (int s = 1; s < NNODE; s <<= 1) {
    int v = t0[tid] + ((tid >= s) ? t0[tid - s] : 0);
    __syncthreads();
    t0[tid] = v;
    __syncthreads();
  }
  offS[tid] = t0[tid] - degS[tid];
  __syncthreads();
  // CSR fill (after fill, offS[i] == end of node i's neighbor list)
  for (int e = tid; e < EEDGE; e += 512) {
    if (maskS[su[e]] & maskS[sv[e]]) {
      int pu = atomicAdd(&offS[su[e]], 1); adj[pu] = sv[e];
      int pv = atomicAdd(&offS[sv[e]], 1); adj[pv] = su[e];
    }
  }
  __syncthreads();
  int myDeg = degS[tid];
  int myEnd = offS[tid];
  int myStart = myEnd - myDeg;
  const int lane = tid & 63;
  const int wvid = tid >> 6;
  wv[tid] = 0.04419417382415922f; // 1/sqrt(512)
  __syncthreads();
  // 64 power iterations: z = L0 w via CSR gather; w = z/(|z|+1e-12)
  for (int it = 0; it < PITERS; ++it) {
    float acc = (float)myDeg * wv[tid];
    for (int p = myStart; p < myEnd; ++p) acc -= wv[adj[p]];
    float sq = acc * acc;
    for (int o = 32; o; o >>= 1) sq += __shfl_xor(sq, o, 64);
    if (lane == 0) red[wvid] = sq;
    __syncthreads(); // also guarantees all wv reads done
    float tot = red[0] + red[1] + red[2] + red[3] + red[4] + red[5] + red[6] + red[7];
    float rn = 1.0f / (sqrtf(tot) + 1e-12f);
    wv[tid] = acc * rn;
    __syncthreads();
  }
  // lam = w . (L0 w); scale = 2/(lam+1e-12)
  {
    float acc = (float)myDeg * wv[tid];
    for (int p = myStart; p < myEnd; ++p) acc -= wv[adj[p]];
    float pr = wv[tid] * acc;
    for (int o = 32; o; o >>= 1) pr += __shfl_xor(pr, o, 64);
    if (lane == 0) red[wvid] = pr;
    __syncthreads();
    if (tid == 0) {
      float lam = red[0] + red[1] + red[2] + red[3] + red[4] + red[5] + red[6] + red[7];
      ws[WS_SCALE + g] = 2.0f / (lam + 1e-12f);
    }
  }
}

// ---------------------------------------------------------------------------
// K7: outputs. Roles by block range:
//   [0,512):      xn = x_n * score_n * mask        (dense, float4)
//   [512,2560):   xe = x_e * score_e * keep        (dense, float4)
//   [2560,2576):  L0 scatter (4 atomics per kept edge)
//   [2576,6672):  L1 pair enumeration over compacted kept edges (unique writes)
__global__ __launch_bounds__(256) void k_out(
    const float* __restrict__ xn, const float* __restrict__ xe,
    const int* __restrict__ edge_u, const int* __restrict__ edge_v,
    const float* __restrict__ ws, float* __restrict__ out) {
  int b = blockIdx.x, tid = threadIdx.x;
  const int* wsi = (const int*)ws;
  if (b < 512) {
    int idx = b * 256 + tid;            // float4 idx over 131072
    int row = idx >> 4;
    float s = ws[WS_SN + row] * (float)wsi[WS_MASK + row];
    float4 x4 = ((const float4*)xn)[idx];
    float4 r = make_float4(x4.x * s, x4.y * s, x4.z * s, x4.w * s);
    ((float4*)(out + O_XN))[idx] = r;
  } else if (b < 2560) {
    int idx = (b - 512) * 256 + tid;    // float4 idx over 524288
    int row = idx >> 4;
    float s = ws[WS_SE + row] * (float)wsi[WS_KEEP + row];
    float4 x4 = ((const float4*)xe)[idx];
    float4 r = make_float4(x4.x * s, x4.y * s, x4.z * s, x4.w * s);
    ((float4*)(out + O_XE))[idx] = r;
  } else if (b < 2576) {
    int g = b - 2560;
    int cnt = wsi[WS_KCNT + g];
    float s = ws[WS_SCALE + g];
    float* L0 = out + O_L0 + (long long)g * (NNODE * NNODE);
    const int* kl = wsi + WS_KLIST + g * EEDGE;
    const int* eu = edge_u + g * EEDGE;
    const int* ev = edge_v + g * EEDGE;
    for (int t = tid; t < cnt; t += 256) {
      int e = kl[t];
      int u = eu[e], v = ev[e];
      atomicAdd(&L0[u * NNODE + u], s);
      atomicAdd(&L0[v * NNODE + v], s);
      atomicAdd(&L0[u * NNODE + v], -s);
      atomicAdd(&L0[v * NNODE + u], -s);
    }
  } else {
    int q = b - 2576;                   // [0, 4096) = 16 graphs x 256 sub-blocks
    int g = q >> 8, sb = q & 255;
    int cnt = wsi[WS_KCNT + g];
    float s = ws[WS_SCALE + g];
    float* L1 = out + O_L1 + (long long)g * (EEDGE * EEDGE);
    const int* kl = wsi + WS_KLIST + g * EEDGE;
    const int* eu = edge_u + g * EEDGE;
    const int* ev = edge_v + g * EEDGE;
    for (int a = sb; a < cnt; a += 256) {
      int e1 = kl[a];
      int u1 = eu[e1], v1 = ev[e1];
      long long rowoff = (long long)e1 * EEDGE;
      for (int b2 = tid; b2 < cnt; b2 += 256) {
        int e2 = kl[b2];
        int u2 = eu[e2], v2 = ev[e2];
        int val = (u1 == u2) + (v1 == v2) - (v1 == u2) - (u1 == v2);
        if (val) L1[rowoff + e2] = s * (float)val;
      }
    }
  }
}

// ---------------------------------------------------------------------------
extern "C" void kernel_launch(void* const* d_in, const int* in_sizes, int n_in,
                              void* d_out, int out_size, void* d_ws, size_t ws_size,
                              hipStream_t stream) {
  const float* x_n = (const float*)d_in[0];
  const float* x_e = (const float*)d_in[1];
  const int* edge_u = (const int*)d_in[2];
  const int* edge_v = (const int*)d_in[3];
  const int* src_n = (const int*)d_in[4];
  const int* dst_n = (const int*)d_in[5];
  const float* ew_n = (const float*)d_in[6];
  const int* src_e = (const int*)d_in[7];
  const int* dst_e = (const int*)d_in[8];
  const float* ew_e = (const float*)d_in[9];
  const float* W_n = (const float*)d_in[10];
  const float* b_n = (const float*)d_in[11];
  const float* W_e = (const float*)d_in[12];
  const float* b_e = (const float*)d_in[13];
  float* ws = (float*)d_ws;
  float* out = (float*)d_out;

  // zero the workspace accumulators (d1/d2/e2, kept counters)
  hipMemsetAsync(d_ws, 0, (size_t)WS_TOTAL * sizeof(float), stream);
  // per-row channel dots (one wave per row)
  k_dots<<<(NNT + NET) / 4, 256, 0, stream>>>(x_n, x_e, W_n, W_e, ws);
  // scalar message passing: d1 = L c1, d2 = L c2
  k_scat1<<<(MN + ME) / 256, 256, 0, stream>>>(src_n, dst_n, ew_n, src_e, dst_e, ew_e, ws);
  // e2 = L d2
  k_scat2<<<(MN + ME) / 256, 256, 0, stream>>>(src_n, dst_n, ew_n, src_e, dst_e, ew_e, ws);
  // fat kernel: pooling (16 blocks) + L0/L1 zero-fill (2048 blocks)
  const int nzb = 2048;
  k_fat<<<16 + nzb, 512, 0, stream>>>(edge_u, edge_v, b_n, b_e, ws, out, nzb);
  // final outputs: dense xn/xe, sparse L0/L1 scatter
  k_out<<<6672, 256, 0, stream>>>(x_n, x_e, edge_u, edge_v, ws, out);
}